// Round 4
// baseline (396.084 us; speedup 1.0000x reference)
//
#include <hip/hip_runtime.h>
#include <hip/hip_bf16.h>
#include <cstdint>
#include <cstddef>

#define N_LEVELS   16
#define LOG2_T     19
#define TABLE_SIZE (1u << LOG2_T)
#define HASH_MASK  (TABLE_SIZE - 1u)
#define PRIME1     2654435761u

#define TPB 256
#define BT  64          // points per block (MLP)
#define FROW 40         // featG row stride in ushorts (80 B): [enc0..31, x, y, 6 zeros]
#define FSTRIDE 72      // fused-fallback feat LDS stride
#define HSTRIDE 264     // h row stride (ushort): 256 + 8 pad

typedef __attribute__((ext_vector_type(8))) short short8;
typedef __attribute__((ext_vector_type(4))) float floatx4;

// floor(16 * (2^(1/3))^l) in fp32 lands exactly on these integers
__device__ __constant__ float c_res[N_LEVELS] = {
    16.f, 20.f, 25.f, 32.f, 40.f, 50.f, 64.f, 80.f,
    101.f, 128.f, 161.f, 203.f, 256.f, 322.f, 406.f, 512.f
};

__device__ __forceinline__ unsigned short f2bf(float x) {
    union { float f; uint32_t u; } v; v.f = x;
    const uint32_t u = v.u;
    return (unsigned short)((u + 0x7fffu + ((u >> 16) & 1u)) >> 16);  // RNE
}

__device__ __forceinline__ uint32_t pk_bf16(float a, float b) {
#if __has_builtin(__builtin_amdgcn_cvt_pk_bf16_f32)
    typedef __attribute__((ext_vector_type(2))) __bf16 bf16x2;
    bf16x2 v = __builtin_amdgcn_cvt_pk_bf16_f32(a, b);
    uint32_t u; __builtin_memcpy(&u, &v, 4); return u;
#else
    return (uint32_t)f2bf(a) | ((uint32_t)f2bf(b) << 16);
#endif
}

// ---------------- weight packing into MFMA fragments ----------------
// Fragment f: lane (q=l>>4, r=l&15) holds W[k = kt*32 + q*8 + j][col = nt*16 + r], j=0..7.
// Used as the MFMA A operand (A[m=r][k=q*8+j] = W^T[m][k]).
__global__ void pack_weights(const float* __restrict__ W0,
                             const float* __restrict__ W1,
                             const float* __restrict__ W2,
                             unsigned short* __restrict__ ws)
{
    const int f = blockIdx.x;       // 0..167
    const int lane = threadIdx.x;   // 0..63
    const int q = lane >> 4, r = lane & 15;
    int layer, kt, nt;
    if (f < 32)       { layer = 0; kt = f >> 4;        nt = f & 15; }
    else if (f < 160) { layer = 1; kt = (f - 32) >> 4; nt = (f - 32) & 15; }
    else              { layer = 2; kt = f - 160;       nt = 0; }
    unsigned short vals[8];
    #pragma unroll
    for (int j = 0; j < 8; ++j) {
        const int k = kt * 32 + q * 8 + j;
        const int n = nt * 16 + r;
        float v = 0.f;
        if (layer == 0) {
            // feat order: [enc0..enc31, x, y, zeros]; original W0 rows: [x, y, enc0..enc31]
            if (k < 32)       v = W0[(2 + k) * 256 + n];
            else if (k == 32) v = W0[0 * 256 + n];
            else if (k == 33) v = W0[1 * 256 + n];
        } else if (layer == 1) {
            v = W1[k * 256 + n];
        } else {
            if (n < 3) v = W2[k * 3 + n];
        }
        vals[j] = f2bf(v);
    }
    uint4 pk;
    pk.x = (uint32_t)vals[0] | ((uint32_t)vals[1] << 16);
    pk.y = (uint32_t)vals[2] | ((uint32_t)vals[3] << 16);
    pk.z = (uint32_t)vals[4] | ((uint32_t)vals[5] << 16);
    pk.w = (uint32_t)vals[6] | ((uint32_t)vals[7] << 16);
    *(uint4*)(ws + (size_t)f * 1024 + lane * 8) = pk;
}

// ---------------- kernel A: hash-grid encoding, lane = point ----------------
// Every gather instruction is level-uniform and corner-uniform -> max same-line
// merging at coarse levels; high occupancy keeps TCP saturated.
__global__ __launch_bounds__(TPB, 4)
void encode_kernel(const float* __restrict__ coord,
                   const float* __restrict__ emb,
                   unsigned short* __restrict__ featG, int npoints)
{
    const int gp = blockIdx.x * TPB + threadIdx.x;
    if (gp >= npoints) return;
    float x = coord[2 * gp + 0];
    float y = coord[2 * gp + 1];
    x = fminf(fmaxf(x, -1.f), 1.f);
    y = fminf(fmaxf(y, -1.f), 1.f);

    uint32_t e[N_LEVELS];
    #pragma unroll
    for (int l = 0; l < N_LEVELS; ++l) {
        const float res  = c_res[l];
        const float grid = 2.0f / res;             // compile-time fp32 constant (matches ref)
        const float invg = res * 0.5f;             // exact
        const float tx = (x + 1.0f) / grid;        // IEEE div -> exact cell match with ref
        const float ty = (y + 1.0f) / grid;
        const int bx = (int)floorf(tx);
        const int by = (int)floorf(ty);
        const float vx = (float)bx * grid - 1.0f;
        const float vy = (float)by * grid - 1.0f;
        const float wx = (x - vx) * invg;
        const float wy = (y - vy) * invg;
        const float2* tab = (const float2*)emb + (size_t)l * TABLE_SIZE;
        const uint32_t ux0 = (uint32_t)bx, ux1 = (uint32_t)(bx + 1);
        const uint32_t hy0 = (uint32_t)by * PRIME1;
        const uint32_t hy1 = (uint32_t)(by + 1) * PRIME1;
        const float2 e00 = tab[(ux0 ^ hy0) & HASH_MASK];
        const float2 e01 = tab[(ux0 ^ hy1) & HASH_MASK];
        const float2 e10 = tab[(ux1 ^ hy0) & HASH_MASK];
        const float2 e11 = tab[(ux1 ^ hy1) & HASH_MASK];
        const float owx = 1.f - wx, owy = 1.f - wy;
        const float f0 = (e00.x * owx + e10.x * wx) * owy + (e01.x * owx + e11.x * wx) * wy;
        const float f1 = (e00.y * owx + e10.y * wx) * owy + (e01.y * owx + e11.y * wx) * wy;
        e[l] = pk_bf16(f0, f1);
    }

    unsigned short* row = featG + (size_t)gp * FROW;
    uint4 v;
    v.x = e[0];  v.y = e[1];  v.z = e[2];  v.w = e[3];  *(uint4*)(row +  0) = v;
    v.x = e[4];  v.y = e[5];  v.z = e[6];  v.w = e[7];  *(uint4*)(row +  8) = v;
    v.x = e[8];  v.y = e[9];  v.z = e[10]; v.w = e[11]; *(uint4*)(row + 16) = v;
    v.x = e[12]; v.y = e[13]; v.z = e[14]; v.w = e[15]; *(uint4*)(row + 24) = v;
    v.x = pk_bf16(x, y); v.y = 0u; v.z = 0u; v.w = 0u;  *(uint4*)(row + 32) = v;
}

// ---------------- kernel B: MLP, B-fragments straight from global featG ----------------
__global__ __launch_bounds__(TPB, 4)
void mlp_kernel(const unsigned short* __restrict__ featG,
                const unsigned short* __restrict__ wpack,
                const float* __restrict__ b0,
                const float* __restrict__ b1,
                const float* __restrict__ b2,
                float* __restrict__ out, int npoints)
{
    __shared__ unsigned short h[BT][HSTRIDE];   // 33792 B -> 4 blocks/CU

    const int t = threadIdx.x;
    const int p0 = blockIdx.x * BT;
    const int wave = t >> 6;
    const int lane = t & 63;
    const int q = lane >> 4, r = lane & 15;

    const unsigned short* w0p = wpack;
    const unsigned short* w1p = wpack + 32 * 1024;
    const unsigned short* w2p = wpack + 160 * 1024;

    // ---------- layer 0 (K=64 padded): W^T x feat^T -> h0[point][neuron] ----------
    {
        floatx4 acc[4][4];   // [mti (neuron tile)][nt (point tile)]
        #pragma unroll
        for (int mti = 0; mti < 4; ++mti)
            #pragma unroll
            for (int nt = 0; nt < 4; ++nt)
                acc[mti][nt] = floatx4{0.f, 0.f, 0.f, 0.f};

        short8 a[4], b[4];
        // kt = 0: k = 0..31 (enc features)
        #pragma unroll
        for (int mti = 0; mti < 4; ++mti)
            a[mti] = *(const short8*)(w0p + (size_t)(0 * 16 + wave * 4 + mti) * 1024 + lane * 8);
        #pragma unroll
        for (int nt = 0; nt < 4; ++nt) {
            const int row = min(p0 + 16 * nt + r, npoints - 1);
            b[nt] = *(const short8*)(featG + (size_t)row * FROW + q * 8);
        }
        #pragma unroll
        for (int mti = 0; mti < 4; ++mti)
            #pragma unroll
            for (int nt = 0; nt < 4; ++nt)
                acc[mti][nt] = __builtin_amdgcn_mfma_f32_16x16x32_bf16(a[mti], b[nt], acc[mti][nt], 0, 0, 0);
        // kt = 1: k = 32..63 (only q==0 lanes carry x,y + zeros; q>=1 are zero pad)
        #pragma unroll
        for (int mti = 0; mti < 4; ++mti)
            a[mti] = *(const short8*)(w0p + (size_t)(1 * 16 + wave * 4 + mti) * 1024 + lane * 8);
        #pragma unroll
        for (int nt = 0; nt < 4; ++nt) {
            if (q == 0) {
                const int row = min(p0 + 16 * nt + r, npoints - 1);
                b[nt] = *(const short8*)(featG + (size_t)row * FROW + 32);
            } else {
                b[nt] = short8{0,0,0,0,0,0,0,0};
            }
        }
        #pragma unroll
        for (int mti = 0; mti < 4; ++mti)
            #pragma unroll
            for (int nt = 0; nt < 4; ++nt)
                acc[mti][nt] = __builtin_amdgcn_mfma_f32_16x16x32_bf16(a[mti], b[nt], acc[mti][nt], 0, 0, 0);

        #pragma unroll
        for (int mti = 0; mti < 4; ++mti) {
            const int col = (wave * 4 + mti) * 16 + 4 * q;
            const float4 bias = *(const float4*)&b0[col];
            #pragma unroll
            for (int nt = 0; nt < 4; ++nt) {
                const floatx4 a4 = acc[mti][nt];
                uint2 v;
                v.x = pk_bf16(fmaxf(a4[0] + bias.x, 0.f), fmaxf(a4[1] + bias.y, 0.f));
                v.y = pk_bf16(fmaxf(a4[2] + bias.z, 0.f), fmaxf(a4[3] + bias.w, 0.f));
                *(uint2*)&h[16 * nt + r][col] = v;
            }
        }
    }
    __syncthreads();

    // ---------- layer 1 (256 -> 256) ----------
    {
        floatx4 acc[4][4];
        #pragma unroll
        for (int mti = 0; mti < 4; ++mti)
            #pragma unroll
            for (int nt = 0; nt < 4; ++nt)
                acc[mti][nt] = floatx4{0.f, 0.f, 0.f, 0.f};
        #pragma unroll 2
        for (int kt = 0; kt < 8; ++kt) {
            short8 a[4], b[4];
            #pragma unroll
            for (int mti = 0; mti < 4; ++mti)
                a[mti] = *(const short8*)(w1p + (size_t)(kt * 16 + wave * 4 + mti) * 1024 + lane * 8);
            #pragma unroll
            for (int nt = 0; nt < 4; ++nt)
                b[nt] = *(const short8*)&h[16 * nt + r][kt * 32 + q * 8];
            #pragma unroll
            for (int mti = 0; mti < 4; ++mti)
                #pragma unroll
                for (int nt = 0; nt < 4; ++nt)
                    acc[mti][nt] = __builtin_amdgcn_mfma_f32_16x16x32_bf16(a[mti], b[nt], acc[mti][nt], 0, 0, 0);
        }
        __syncthreads();   // all reads of h0 done before overwrite
        #pragma unroll
        for (int mti = 0; mti < 4; ++mti) {
            const int col = (wave * 4 + mti) * 16 + 4 * q;
            const float4 bias = *(const float4*)&b1[col];
            #pragma unroll
            for (int nt = 0; nt < 4; ++nt) {
                const floatx4 a4 = acc[mti][nt];
                uint2 v;
                v.x = pk_bf16(fmaxf(a4[0] + bias.x, 0.f), fmaxf(a4[1] + bias.y, 0.f));
                v.y = pk_bf16(fmaxf(a4[2] + bias.z, 0.f), fmaxf(a4[3] + bias.w, 0.f));
                *(uint2*)&h[16 * nt + r][col] = v;
            }
        }
    }
    __syncthreads();

    // ---------- layer 2 (256 -> 3), sigmoid, store ----------
    {
        floatx4 acc = floatx4{0.f, 0.f, 0.f, 0.f};
        #pragma unroll
        for (int kt = 0; kt < 8; ++kt) {
            const short8 a = *(const short8*)(w2p + (size_t)kt * 1024 + lane * 8);
            const short8 b = *(const short8*)&h[16 * wave + r][kt * 32 + q * 8];
            acc = __builtin_amdgcn_mfma_f32_16x16x32_bf16(a, b, acc, 0, 0, 0);
        }
        if (q == 0) {
            const int gp = p0 + 16 * wave + r;
            if (gp < npoints) {
                #pragma unroll
                for (int reg = 0; reg < 3; ++reg) {
                    const float s = acc[reg] + b2[reg];
                    out[(size_t)gp * 3 + reg] = 1.f / (1.f + expf(-s));
                }
            }
        }
    }
}

// ---------------- fused fallback (round-3 path) if ws is too small ----------------
__global__ __launch_bounds__(TPB, 2)
void fused_ngp_mlp(const float* __restrict__ coord,
                   const float* __restrict__ emb,
                   const unsigned short* __restrict__ wpack,
                   const float* __restrict__ b0,
                   const float* __restrict__ b1,
                   const float* __restrict__ b2,
                   float* __restrict__ out, int npoints)
{
    __shared__ unsigned short feat[BT][FSTRIDE];
    __shared__ unsigned short h[BT][HSTRIDE];

    const int t = threadIdx.x;
    const int p0 = blockIdx.x * BT;
    const int wave = t >> 6;
    const int lane = t & 63;
    const int q = lane >> 4, r = lane & 15;

    {
        const int p = t >> 2;
        const int k = t & 3;
        const int gp = p0 + p;
        float x = 0.f, y = 0.f;
        if (gp < npoints) {
            x = coord[2 * gp + 0]; y = coord[2 * gp + 1];
            x = fminf(fmaxf(x, -1.f), 1.f);
            y = fminf(fmaxf(y, -1.f), 1.f);
        }
        if (k == 0) {
            feat[p][32] = f2bf(x); feat[p][33] = f2bf(y);
            *(uint32_t*)&feat[p][34] = 0u;
            *(uint32_t*)&feat[p][36] = 0u;
            *(uint32_t*)&feat[p][38] = 0u;
        } else {
            const uint4 z = {0u, 0u, 0u, 0u};
            *(uint4*)&feat[p][40 + 8 * (k - 1)] = z;
        }
        #pragma unroll
        for (int i = 0; i < 4; ++i) {
            const int l = 4 * k + i;
            const float res  = c_res[l];
            const float grid = 2.0f / res;
            const float invg = res * 0.5f;
            const float tx = (x + 1.0f) / grid;
            const float ty = (y + 1.0f) / grid;
            const int bx = (int)floorf(tx);
            const int by = (int)floorf(ty);
            const float vx = (float)bx * grid - 1.0f;
            const float vy = (float)by * grid - 1.0f;
            const float wx = (x - vx) * invg;
            const float wy = (y - vy) * invg;
            const float2* tab = (const float2*)emb + (size_t)l * TABLE_SIZE;
            const uint32_t ux0 = (uint32_t)bx, ux1 = (uint32_t)(bx + 1);
            const uint32_t hy0 = (uint32_t)by * PRIME1;
            const uint32_t hy1 = (uint32_t)(by + 1) * PRIME1;
            const float2 e00 = tab[(ux0 ^ hy0) & HASH_MASK];
            const float2 e01 = tab[(ux0 ^ hy1) & HASH_MASK];
            const float2 e10 = tab[(ux1 ^ hy0) & HASH_MASK];
            const float2 e11 = tab[(ux1 ^ hy1) & HASH_MASK];
            const float owx = 1.f - wx, owy = 1.f - wy;
            const float f0 = (e00.x * owx + e10.x * wx) * owy + (e01.x * owx + e11.x * wx) * wy;
            const float f1 = (e00.y * owx + e10.y * wx) * owy + (e01.y * owx + e11.y * wx) * wy;
            *(uint32_t*)&feat[p][8 * k + 2 * i] = pk_bf16(f0, f1);
        }
    }
    __syncthreads();

    const unsigned short* w0p = wpack;
    const unsigned short* w1p = wpack + 32 * 1024;
    const unsigned short* w2p = wpack + 160 * 1024;

    {
        floatx4 acc[4][4];
        #pragma unroll
        for (int mti = 0; mti < 4; ++mti)
            #pragma unroll
            for (int nt = 0; nt < 4; ++nt)
                acc[mti][nt] = floatx4{0.f, 0.f, 0.f, 0.f};
        #pragma unroll
        for (int kt = 0; kt < 2; ++kt) {
            short8 a[4], b[4];
            #pragma unroll
            for (int mti = 0; mti < 4; ++mti)
                a[mti] = *(const short8*)(w0p + (size_t)(kt * 16 + wave * 4 + mti) * 1024 + lane * 8);
            #pragma unroll
            for (int nt = 0; nt < 4; ++nt)
                b[nt] = *(const short8*)&feat[16 * nt + r][kt * 32 + q * 8];
            #pragma unroll
            for (int mti = 0; mti < 4; ++mti)
                #pragma unroll
                for (int nt = 0; nt < 4; ++nt)
                    acc[mti][nt] = __builtin_amdgcn_mfma_f32_16x16x32_bf16(a[mti], b[nt], acc[mti][nt], 0, 0, 0);
        }
        #pragma unroll
        for (int mti = 0; mti < 4; ++mti) {
            const int col = (wave * 4 + mti) * 16 + 4 * q;
            const float4 bias = *(const float4*)&b0[col];
            #pragma unroll
            for (int nt = 0; nt < 4; ++nt) {
                const floatx4 a4 = acc[mti][nt];
                uint2 v;
                v.x = pk_bf16(fmaxf(a4[0] + bias.x, 0.f), fmaxf(a4[1] + bias.y, 0.f));
                v.y = pk_bf16(fmaxf(a4[2] + bias.z, 0.f), fmaxf(a4[3] + bias.w, 0.f));
                *(uint2*)&h[16 * nt + r][col] = v;
            }
        }
    }
    __syncthreads();

    {
        floatx4 acc[4][4];
        #pragma unroll
        for (int mti = 0; mti < 4; ++mti)
            #pragma unroll
            for (int nt = 0; nt < 4; ++nt)
                acc[mti][nt] = floatx4{0.f, 0.f, 0.f, 0.f};
        #pragma unroll 2
        for (int kt = 0; kt < 8; ++kt) {
            short8 a[4], b[4];
            #pragma unroll
            for (int mti = 0; mti < 4; ++mti)
                a[mti] = *(const short8*)(w1p + (size_t)(kt * 16 + wave * 4 + mti) * 1024 + lane * 8);
            #pragma unroll
            for (int nt = 0; nt < 4; ++nt)
                b[nt] = *(const short8*)&h[16 * nt + r][kt * 32 + q * 8];
            #pragma unroll
            for (int mti = 0; mti < 4; ++mti)
                #pragma unroll
                for (int nt = 0; nt < 4; ++nt)
                    acc[mti][nt] = __builtin_amdgcn_mfma_f32_16x16x32_bf16(a[mti], b[nt], acc[mti][nt], 0, 0, 0);
        }
        __syncthreads();
        #pragma unroll
        for (int mti = 0; mti < 4; ++mti) {
            const int col = (wave * 4 + mti) * 16 + 4 * q;
            const float4 bias = *(const float4*)&b1[col];
            #pragma unroll
            for (int nt = 0; nt < 4; ++nt) {
                const floatx4 a4 = acc[mti][nt];
                uint2 v;
                v.x = pk_bf16(fmaxf(a4[0] + bias.x, 0.f), fmaxf(a4[1] + bias.y, 0.f));
                v.y = pk_bf16(fmaxf(a4[2] + bias.z, 0.f), fmaxf(a4[3] + bias.w, 0.f));
                *(uint2*)&h[16 * nt + r][col] = v;
            }
        }
    }
    __syncthreads();

    {
        floatx4 acc = floatx4{0.f, 0.f, 0.f, 0.f};
        #pragma unroll
        for (int kt = 0; kt < 8; ++kt) {
            const short8 a = *(const short8*)(w2p + (size_t)kt * 1024 + lane * 8);
            const short8 b = *(const short8*)&h[16 * wave + r][kt * 32 + q * 8];
            acc = __builtin_amdgcn_mfma_f32_16x16x32_bf16(a, b, acc, 0, 0, 0);
        }
        if (q == 0) {
            const int gp = p0 + 16 * wave + r;
            if (gp < npoints) {
                #pragma unroll
                for (int reg = 0; reg < 3; ++reg) {
                    const float s = acc[reg] + b2[reg];
                    out[(size_t)gp * 3 + reg] = 1.f / (1.f + expf(-s));
                }
            }
        }
    }
}

extern "C" void kernel_launch(void* const* d_in, const int* in_sizes, int n_in,
                              void* d_out, int out_size, void* d_ws, size_t ws_size,
                              hipStream_t stream) {
    const float* coord = (const float*)d_in[0];
    const float* emb   = (const float*)d_in[1];
    const float* W0    = (const float*)d_in[2];
    const float* b0    = (const float*)d_in[3];
    const float* W1    = (const float*)d_in[4];
    const float* b1    = (const float*)d_in[5];
    const float* W2    = (const float*)d_in[6];
    const float* b2    = (const float*)d_in[7];
    float* out = (float*)d_out;
    unsigned short* ws = (unsigned short*)d_ws;

    const int npoints = in_sizes[0] / 2;
    const int mlp_blocks = (npoints + BT - 1) / BT;

    const size_t pack_ushorts = 168u * 1024u;                 // 344 KB of weight frags
    const size_t need_bytes = (pack_ushorts + (size_t)npoints * FROW) * sizeof(unsigned short);

    hipLaunchKernelGGL(pack_weights, dim3(168), dim3(64), 0, stream, W0, W1, W2, ws);

    if (ws_size >= need_bytes) {
        unsigned short* featG = ws + pack_ushorts;
        const int enc_blocks = (npoints + TPB - 1) / TPB;
        hipLaunchKernelGGL(encode_kernel, dim3(enc_blocks), dim3(TPB), 0, stream,
                           coord, emb, featG, npoints);
        hipLaunchKernelGGL(mlp_kernel, dim3(mlp_blocks), dim3(TPB), 0, stream,
                           featG, ws, b0, b1, b2, out, npoints);
    } else {
        hipLaunchKernelGGL(fused_ngp_mlp, dim3(mlp_blocks), dim3(TPB), 0, stream,
                           coord, emb, ws, b0, b1, b2, out, npoints);
    }
}